// Round 1
// baseline (667.782 us; speedup 1.0000x reference)
//
#include <hip/hip_runtime.h>
#include <hip/hip_bf16.h>

// ============================================================================
// IDASR pipeline on gfx950.
// All conv/MLP stages run as bf16 MFMA GEMMs: C = A(M,K) * Bt(N,K)^T (+bias).
// Per-query sampling/attention in fp32 scalar kernels.
// Workspace plan (~134 MB): early scratch region is aliased by feat_in later.
// ============================================================================

typedef unsigned short u16;
using frag_ab = __attribute__((ext_vector_type(8))) short;  // 8 x bf16
using frag_cd = __attribute__((ext_vector_type(4))) float;  // 4 x f32 acc

#define HW 4096   // 64*64 spatial
#define NQ 4096   // queries

static __device__ __forceinline__ u16 f2b(float f) {
  union { __hip_bfloat16 h; u16 u; } c; c.h = __float2bfloat16(f); return c.u;
}

// ---------------------------------------------------------------------------
// Generic bf16 GEMM: C[M,N] = A[M,K] * Bt[N,K]^T (+bias[n]) (+relu) ->f32/bf16
// Tile 64x64, BK=32, 256 threads = 4 waves, each wave a 32x32 quadrant
// (2x2 MFMA 16x16x32 tiles). M assumed multiple of 64 (always 4096 here).
// N bounds-checked. K multiple of 32 (padded at pack time). Batched via z.
// ---------------------------------------------------------------------------
#define BM 64
#define BN 64
#define BK 32
#define LDSS 40   // lds row stride (elems): 32 + 8 pad

__global__ __launch_bounds__(256)
void gemm_bt(const u16* __restrict__ A, const u16* __restrict__ Bt,
             void* __restrict__ Cv, const float* __restrict__ bias,
             int N, int K, int ldc, int flags,   // flags: 1=relu, 2=bf16 out
             long sA, long sB, long sC, int sBias)
{
  __shared__ u16 As[BM * LDSS];
  __shared__ u16 Bs[BN * LDSS];
  const int z = blockIdx.z;
  A  += (long)z * sA;
  Bt += (long)z * sB;
  const float* bz = bias ? bias + (long)z * sBias : nullptr;

  const int tid  = threadIdx.x;
  const int m0   = blockIdx.x * BM;
  const int n0   = blockIdx.y * BN;
  const int wave = tid >> 6, lane = tid & 63;
  const int mw = (wave & 1) * 32, nw = (wave >> 1) * 32;
  const int lr = lane & 15, lk = lane >> 4;
  const int srow = tid >> 2, scol = (tid & 3) * 8;   // staging: 64 rows x 4 x 8elem

  frag_cd acc[2][2] = {};
  const u16* aptr = A + (size_t)(m0 + srow) * K + scol;
  const bool bok  = (n0 + srow) < N;
  const u16* bptr = Bt + (size_t)(n0 + srow) * K + scol;

  for (int k0 = 0; k0 < K; k0 += BK) {
    uint4 av = *(const uint4*)(aptr + k0);
    uint4 bv = bok ? *(const uint4*)(bptr + k0) : uint4{0u, 0u, 0u, 0u};
    *(uint4*)&As[srow * LDSS + scol] = av;
    *(uint4*)&Bs[srow * LDSS + scol] = bv;
    __syncthreads();
    frag_ab af0 = *(const frag_ab*)&As[(mw      + lr) * LDSS + lk * 8];
    frag_ab af1 = *(const frag_ab*)&As[(mw + 16 + lr) * LDSS + lk * 8];
    frag_ab bf0 = *(const frag_ab*)&Bs[(nw      + lr) * LDSS + lk * 8];
    frag_ab bf1 = *(const frag_ab*)&Bs[(nw + 16 + lr) * LDSS + lk * 8];
    acc[0][0] = __builtin_amdgcn_mfma_f32_16x16x32_bf16(af0, bf0, acc[0][0], 0, 0, 0);
    acc[0][1] = __builtin_amdgcn_mfma_f32_16x16x32_bf16(af0, bf1, acc[0][1], 0, 0, 0);
    acc[1][0] = __builtin_amdgcn_mfma_f32_16x16x32_bf16(af1, bf0, acc[1][0], 0, 0, 0);
    acc[1][1] = __builtin_amdgcn_mfma_f32_16x16x32_bf16(af1, bf1, acc[1][1], 0, 0, 0);
    __syncthreads();
  }

  const bool relu = flags & 1;
  const bool obf  = flags & 2;
  #pragma unroll
  for (int i = 0; i < 2; i++)
    #pragma unroll
    for (int j = 0; j < 2; j++) {
      int col = n0 + nw + j * 16 + lr;        // C/D: col = lane&15
      if (col >= N) continue;
      float badd = bz ? bz[col] : 0.f;
      #pragma unroll
      for (int r = 0; r < 4; r++) {
        int row = m0 + mw + i * 16 + lk * 4 + r;  // C/D: row = (lane>>4)*4+reg
        float v = acc[i][j][r] + badd;
        if (relu) v = fmaxf(v, 0.f);
        size_t idx = (size_t)z * sC + (size_t)row * ldc + col;
        if (obf) ((u16*)Cv)[idx] = f2b(v);
        else     ((float*)Cv)[idx] = v;
      }
    }
}

// ---------------------------------------------------------------------------
// Weight packing
// ---------------------------------------------------------------------------
// conv weights (O, Cin, K2) f32 -> Bt[o][s*Cin+ci] bf16
__global__ void pack_conv_w(const float* __restrict__ W, u16* __restrict__ Bt,
                            int O, int Cin, int K2)
{
  int idx = blockIdx.x * 256 + threadIdx.x;
  if (idx >= O * Cin * K2) return;
  int o  = idx / (Cin * K2);
  int r  = idx - o * (Cin * K2);
  int ci = r / K2;
  int s  = r - ci * K2;
  Bt[(size_t)o * (Cin * K2) + s * Cin + ci] = f2b(W[idx]);
}

// dense (N,Kin) f32 -> (N,Kout) bf16, zero-padded K
__global__ void pack_cast(const float* __restrict__ W, u16* __restrict__ Bt,
                          int N, int Kin, int Kout)
{
  int idx = blockIdx.x * 256 + threadIdx.x;
  if (idx >= N * Kout) return;
  int n = idx / Kout, k = idx - n * Kout;
  Bt[idx] = f2b(k < Kin ? W[(size_t)n * Kin + k] : 0.f);
}

__global__ void pack_bias3(const float* __restrict__ a, const float* __restrict__ b,
                           const float* __restrict__ c, float* __restrict__ out)
{
  int i = blockIdx.x * 256 + threadIdx.x;
  if (i < 256) out[i] = a[i];
  else if (i < 512) out[i] = b[i - 256];
  else if (i < 768) out[i] = c[i - 512];
}

// ---------------------------------------------------------------------------
// Encoder conv: 3->64, 3x3 pad1, +bias, relu -> feat1 (HW,64) bf16
// ---------------------------------------------------------------------------
__global__ __launch_bounds__(64)
void conv_enc(const float* __restrict__ inp, const float* __restrict__ W,
              const float* __restrict__ b, u16* __restrict__ feat1)
{
  const int p = blockIdx.x, c = threadIdx.x;
  const int y = p >> 6, x = p & 63;
  float s = b[c];
  #pragma unroll
  for (int ci = 0; ci < 3; ci++)
    #pragma unroll
    for (int dy = 0; dy < 3; dy++) {
      int yy = y + dy - 1;
      if ((unsigned)yy >= 64u) continue;
      #pragma unroll
      for (int dx = 0; dx < 3; dx++) {
        int xx = x + dx - 1;
        if ((unsigned)xx >= 64u) continue;
        s += inp[ci * HW + yy * 64 + xx] * W[((c * 3 + ci) * 3 + dy) * 3 + dx];
      }
    }
  feat1[(size_t)p * 64 + c] = f2b(fmaxf(s, 0.f));
}

// im2col 3x3 pad1: X (HW,C) bf16 -> Y (HW, 9C), k = s*C+c. grid (HW,9), block C
__global__ void im2col3(const u16* __restrict__ X, u16* __restrict__ Y, int C)
{
  const int p = blockIdx.x, s = blockIdx.y, c = threadIdx.x;
  const int y = p >> 6, x = p & 63;
  const int yy = y + s / 3 - 1, xx = x + s % 3 - 1;
  u16 v = (((unsigned)yy < 64u) && ((unsigned)xx < 64u))
              ? X[(size_t)(yy * 64 + xx) * C + c] : (u16)0;
  Y[(size_t)p * (9 * C) + s * C + c] = v;
}

// im2col 5x5 pad2 grouped: feat (HW,256) -> Yg[g][p][s*32+ci], grid (HW,4,8),
// block (32,8)
__global__ void im2col5(const u16* __restrict__ feat, u16* __restrict__ Yg)
{
  const int p = blockIdx.x, g = blockIdx.z;
  const int s = blockIdx.y * 8 + threadIdx.y;
  if (s >= 25) return;
  const int ci = threadIdx.x;
  const int y = p >> 6, x = p & 63;
  const int yy = y + s / 5 - 2, xx = x + s % 5 - 2;
  u16 v = (((unsigned)yy < 64u) && ((unsigned)xx < 64u))
              ? feat[(size_t)(yy * 64 + xx) * 256 + g * 32 + ci] : (u16)0;
  Yg[((size_t)g * HW + p) * 800 + s * 32 + ci] = v;
}

// ---------------------------------------------------------------------------
// LayerNorm(channel) + exact GELU: obuf (HW,256) f32 -> ocg (HW,256) bf16
// ---------------------------------------------------------------------------
__global__ __launch_bounds__(256)
void ln_gelu(const float* __restrict__ x, const float* __restrict__ g,
             const float* __restrict__ b, u16* __restrict__ y)
{
  const int p = blockIdx.x, c = threadIdx.x;
  __shared__ float r1[4], r2[4];
  float v = x[(size_t)p * 256 + c];
  float s1 = v, s2 = v * v;
  #pragma unroll
  for (int off = 32; off; off >>= 1) {
    s1 += __shfl_xor(s1, off);
    s2 += __shfl_xor(s2, off);
  }
  if ((c & 63) == 0) { r1[c >> 6] = s1; r2[c >> 6] = s2; }
  __syncthreads();
  float t1 = r1[0] + r1[1] + r1[2] + r1[3];
  float t2 = r2[0] + r2[1] + r2[2] + r2[3];
  float mu  = t1 * (1.f / 256.f);
  float var = t2 * (1.f / 256.f) - mu * mu;
  float xn = (v - mu) * rsqrtf(var + 1e-5f) * g[c] + b[c];
  float ge = 0.5f * xn * (1.f + erff(xn * 0.70710678118654752f));
  y[(size_t)p * 256 + c] = f2b(ge);
}

// ---------------------------------------------------------------------------
// Per-query sampler: nearest anchor, offsets->tanh, 49 sample coords, rel,
// k/v gather indices, bilinear q sample, q.k dots, bilinear-border skip.
// block 256 = channels, grid NQ.
// ---------------------------------------------------------------------------
__global__ __launch_bounds__(256)
void sampler(const float* __restrict__ coord, const float* __restrict__ fqkv,
             const float* __restrict__ offs, const float* __restrict__ inp,
             float* __restrict__ attnval, u16* __restrict__ relbuf,
             int* __restrict__ vidx, float* __restrict__ skipb)
{
  const int q = blockIdx.x;
  const int tid = threadIdx.x;
  __shared__ float s_off[98];
  __shared__ int s_idx[49];

  const float c0 = coord[q * 2], c1 = coord[q * 2 + 1];
  // grid x comes from coord[...,1], grid y from coord[...,0]  (g = sc[...,::-1])
  const float gxp = ((c1 + 1.f) * 64.f - 1.f) * 0.5f;
  const float gyp = ((c0 + 1.f) * 64.f - 1.f) * 0.5f;
  const int ixn = (int)rintf(gxp), iyn = (int)rintf(gyp);  // round half-even
  const bool inn = ((unsigned)ixn < 64u) && ((unsigned)iyn < 64u);

  if (tid < 98) {
    float v = inn ? offs[(size_t)(iyn * 64 + ixn) * 98 + tid] : 0.f;
    s_off[tid] = tanhf(v) * (2.f / 63.f);
  }
  __syncthreads();

  const float scky = inn ? (-1.f + (float)(2 * iyn + 1) * (1.f / 64.f)) : 0.f;
  const float sckx = inn ? (-1.f + (float)(2 * ixn + 1) * (1.f / 64.f)) : 0.f;

  if (tid < 49) {
    const int a = tid / 7, bb = tid - a * 7;
    float sy = scky + (float)(a - 3) * (2.f / 64.f) + s_off[2 * tid];
    float sx = sckx + (float)(bb - 3) * (2.f / 64.f) + s_off[2 * tid + 1];
    relbuf[(size_t)q * 128 + 2 * tid]     = f2b((c0 - sy) * 64.f);
    relbuf[(size_t)q * 128 + 2 * tid + 1] = f2b((c1 - sx) * 64.f);
    float gx2 = ((sx + 1.f) * 64.f - 1.f) * 0.5f;
    float gy2 = ((sy + 1.f) * 64.f - 1.f) * 0.5f;
    int ix2 = (int)rintf(gx2), iy2 = (int)rintf(gy2);
    int id = (((unsigned)ix2 < 64u) && ((unsigned)iy2 < 64u)) ? (iy2 * 64 + ix2) : -1;
    s_idx[tid] = id;
    vidx[q * 49 + tid] = id;
  } else if (tid >= 98 && tid < 128) {
    relbuf[(size_t)q * 128 + tid] = 0;  // zero pad K 98..127
  }
  __syncthreads();

  // bilinear q sample (zeros padding)
  const float x0f = floorf(gxp), y0f = floorf(gyp);
  const float wx = gxp - x0f, wy = gyp - y0f;
  const int x0 = (int)x0f, y0 = (int)y0f;
  float qc = 0.f;
  #pragma unroll
  for (int t = 0; t < 4; t++) {
    int xi = x0 + (t & 1), yi = y0 + (t >> 1);
    if (((unsigned)xi < 64u) && ((unsigned)yi < 64u)) {
      float w = ((t & 1) ? wx : 1.f - wx) * ((t >> 1) ? wy : 1.f - wy);
      qc += w * fqkv[(size_t)(yi * 64 + xi) * 768 + tid];
    }
  }
  qc *= 0.17677669529663687f;  // 1/sqrt(32)

  const int h = tid >> 5;
  for (int k = 0; k < 49; k++) {
    int id = s_idx[k];
    float kv = (id >= 0) ? fqkv[(size_t)id * 768 + 256 + tid] : 0.f;
    float p = qc * kv;
    p += __shfl_down(p, 16, 32);
    p += __shfl_down(p, 8, 32);
    p += __shfl_down(p, 4, 32);
    p += __shfl_down(p, 2, 32);
    p += __shfl_down(p, 1, 32);
    if ((tid & 31) == 0) attnval[((size_t)q * 49 + k) * 8 + h] = p;
  }

  // skip: bilinear border sample of inp (3 ch)
  if (tid < 3) {
    float gx = fminf(fmaxf(gxp, 0.f), 63.f);
    float gy = fminf(fmaxf(gyp, 0.f), 63.f);
    float xf = floorf(gx), yf = floorf(gy);
    float wxs = gx - xf, wys = gy - yf;
    int xa = (int)xf, ya = (int)yf;
    int xb = min(xa + 1, 63), yb = min(ya + 1, 63);
    const float* ch = inp + tid * HW;
    float v = (1.f - wxs) * (1.f - wys) * ch[ya * 64 + xa]
            + wxs * (1.f - wys) * ch[ya * 64 + xb]
            + (1.f - wxs) * wys * ch[yb * 64 + xa]
            + wxs * wys * ch[yb * 64 + xb];
    skipb[q * 3 + tid] = v;
  }
}

// ---------------------------------------------------------------------------
// wcoord layer2 (49 outputs over 256 hidden) + softmax over 49 per head.
// block 512 (8 waves = 8 heads), grid NQ. attnval updated in-place.
// ---------------------------------------------------------------------------
__global__ __launch_bounds__(512)
void wcoord_softmax(const float* __restrict__ hid1, const float* __restrict__ Wc2,
                    const float* __restrict__ bc2, float* __restrict__ attnval)
{
  const int q = blockIdx.x;
  const int tid = threadIdx.x;
  __shared__ float sh[256];
  __shared__ float swc[49];
  if (tid < 256) sh[tid] = hid1[(size_t)q * 256 + tid];
  __syncthreads();
  if (tid < 49) {
    float s = bc2[tid];
    const float* w = Wc2 + tid * 256;
    for (int i = 0; i < 256; i++) s += sh[i] * w[i];
    swc[tid] = s;
  }
  __syncthreads();
  const int hh = tid >> 6, l = tid & 63;
  float v = (l < 49) ? swc[l] + attnval[((size_t)q * 49 + l) * 8 + hh] : -1e30f;
  float m = v;
  #pragma unroll
  for (int off = 32; off; off >>= 1) m = fmaxf(m, __shfl_xor(m, off));
  float e = (l < 49) ? expf(v - m) : 0.f;
  float s = e;
  #pragma unroll
  for (int off = 32; off; off >>= 1) s += __shfl_xor(s, off);
  if (l < 49) attnval[((size_t)q * 49 + l) * 8 + hh] = e / s;
}

// ---------------------------------------------------------------------------
// feat_in assembly: (v * attn) -> (NQ, 12576) bf16 (padded), + rel_cell tail.
// grid (NQ, 50), block 256.
// ---------------------------------------------------------------------------
__global__ __launch_bounds__(256)
void assemble(const float* __restrict__ fqkv, const float* __restrict__ attnval,
              const int* __restrict__ vidx, const float* __restrict__ cell,
              u16* __restrict__ featin)
{
  const int q = blockIdx.x, j = blockIdx.y, c = threadIdx.x;
  size_t base = (size_t)q * 12576;
  if (j < 49) {
    int id = vidx[q * 49 + j];
    float w = attnval[((size_t)q * 49 + j) * 8 + (c >> 5)];
    float v = (id >= 0) ? fqkv[(size_t)id * 768 + 512 + c] : 0.f;
    featin[base + j * 256 + c] = f2b(v * w);
  } else if (c < 32) {
    float v = (c < 2) ? cell[q * 2 + c] * 64.f : 0.f;
    featin[base + 12544 + c] = f2b(v);
  }
}

// ---------------------------------------------------------------------------
// Final: pred = hid2 @ Wi2^T + bi2 + skip. block 256, grid NQ.
// ---------------------------------------------------------------------------
__global__ __launch_bounds__(256)
void final_out(const float* __restrict__ hid2, const float* __restrict__ Wi2,
               const float* __restrict__ bi2, const float* __restrict__ skipb,
               float* __restrict__ out)
{
  const int q = blockIdx.x, c = threadIdx.x;
  __shared__ float part[3][4];
  float hv = hid2[(size_t)q * 256 + c];
  float p0 = hv * Wi2[c], p1 = hv * Wi2[256 + c], p2 = hv * Wi2[512 + c];
  #pragma unroll
  for (int off = 32; off; off >>= 1) {
    p0 += __shfl_xor(p0, off);
    p1 += __shfl_xor(p1, off);
    p2 += __shfl_xor(p2, off);
  }
  if ((c & 63) == 0) {
    int w = c >> 6;
    part[0][w] = p0; part[1][w] = p1; part[2][w] = p2;
  }
  __syncthreads();
  if (c < 3)
    out[q * 3 + c] = bi2[c] + skipb[q * 3 + c]
                   + part[c][0] + part[c][1] + part[c][2] + part[c][3];
}

// ===========================================================================
extern "C" void kernel_launch(void* const* d_in, const int* in_sizes, int n_in,
                              void* d_out, int out_size, void* d_ws, size_t ws_size,
                              hipStream_t stream)
{
  const float* inp    = (const float*)d_in[0];
  const float* coord  = (const float*)d_in[1];
  const float* cell   = (const float*)d_in[2];
  const float* W_enc  = (const float*)d_in[3];
  const float* b_enc  = (const float*)d_in[4];
  const float* W_ch   = (const float*)d_in[5];
  const float* b_ch   = (const float*)d_in[6];
  const float* W_q    = (const float*)d_in[7];
  const float* b_q    = (const float*)d_in[8];
  const float* W_k    = (const float*)d_in[9];
  const float* b_k    = (const float*)d_in[10];
  const float* W_v    = (const float*)d_in[11];
  const float* b_v    = (const float*)d_in[12];
  const float* W_off1 = (const float*)d_in[13];
  const float* b_off1 = (const float*)d_in[14];
  const float* ln_g   = (const float*)d_in[15];
  const float* ln_b   = (const float*)d_in[16];
  const float* W_off2 = (const float*)d_in[17];
  const float* Wc1    = (const float*)d_in[18];
  const float* bc1    = (const float*)d_in[19];
  const float* Wc2    = (const float*)d_in[20];
  const float* bc2    = (const float*)d_in[21];
  const float* Wi1    = (const float*)d_in[22];
  const float* bi1    = (const float*)d_in[23];
  const float* Wi2    = (const float*)d_in[24];
  const float* bi2    = (const float*)d_in[25];

  char* base = (char*)d_ws;
  size_t off = 0;
  auto alloc = [&](size_t bytes) -> char* {
    char* r = base + off;
    off = (off + bytes + 255) & ~(size_t)255;
    return r;
  };

  // --- scratch region (everything here is dead before feat_in is written) ---
  size_t region0 = off;
  u16*   A2     = (u16*)  alloc((size_t)HW * 2304 * 2);
  u16*   Ag     = (u16*)  alloc((size_t)8 * HW * 800 * 2);
  float* obuf   = (float*)alloc((size_t)HW * 256 * 4);
  u16*   ocg    = (u16*)  alloc((size_t)HW * 256 * 2);
  float* offsb  = (float*)alloc((size_t)HW * 98 * 4);
  u16*   feat1  = (u16*)  alloc((size_t)HW * 64 * 2);
  u16*   A1     = (u16*)  alloc((size_t)HW * 576 * 2);
  u16*   feat   = (u16*)  alloc((size_t)HW * 256 * 2);
  float* hid1   = (float*)alloc((size_t)NQ * 256 * 4);
  u16*   relbuf = (u16*)  alloc((size_t)NQ * 128 * 2);
  u16*   Btqkv  = (u16*)  alloc((size_t)768 * 2304 * 2);
  u16*   Btch   = (u16*)  alloc((size_t)256 * 576 * 2);
  u16*   Btoff1 = (u16*)  alloc((size_t)256 * 800 * 2);
  u16*   Btoff2 = (u16*)  alloc((size_t)98 * 256 * 2);
  u16*   Btc1   = (u16*)  alloc((size_t)256 * 128 * 2);
  // feat_in aliases the scratch region
  u16* featin = (u16*)(base + region0);
  size_t featin_bytes = (size_t)NQ * 12576 * 2;
  if (off - region0 < featin_bytes)
    off = region0 + ((featin_bytes + 255) & ~(size_t)255);
  // --- persistent buffers ---
  float* fqkv    = (float*)alloc((size_t)HW * 768 * 4);
  float* attnval = (float*)alloc((size_t)NQ * 49 * 8 * 4);
  int*   vidxb   = (int*)  alloc((size_t)NQ * 49 * 4);
  float* skipb   = (float*)alloc((size_t)NQ * 3 * 4);
  float* hid2    = (float*)alloc((size_t)NQ * 256 * 4);
  u16*   Wi1p    = (u16*)  alloc((size_t)256 * 12576 * 2);
  float* bqkv    = (float*)alloc(768 * 4);
  (void)ws_size; (void)in_sizes; (void)n_in; (void)out_size;

  // --- weight packing ---
  pack_conv_w<<<(256 * 64 * 9 + 255) / 256, 256, 0, stream>>>(W_ch, Btch, 256, 64, 9);
  pack_conv_w<<<(256 * 256 * 9 + 255) / 256, 256, 0, stream>>>(W_q, Btqkv, 256, 256, 9);
  pack_conv_w<<<(256 * 256 * 9 + 255) / 256, 256, 0, stream>>>(W_k, Btqkv + (size_t)256 * 2304, 256, 256, 9);
  pack_conv_w<<<(256 * 256 * 9 + 255) / 256, 256, 0, stream>>>(W_v, Btqkv + (size_t)512 * 2304, 256, 256, 9);
  pack_conv_w<<<(256 * 32 * 25 + 255) / 256, 256, 0, stream>>>(W_off1, Btoff1, 256, 32, 25);
  pack_cast<<<(98 * 256 + 255) / 256, 256, 0, stream>>>(W_off2, Btoff2, 98, 256, 256);
  pack_cast<<<(256 * 128 + 255) / 256, 256, 0, stream>>>(Wc1, Btc1, 256, 98, 128);
  pack_cast<<<(256 * 12576 + 255) / 256, 256, 0, stream>>>(Wi1, Wi1p, 256, 12546, 12576);
  pack_bias3<<<3, 256, 0, stream>>>(b_q, b_k, b_v, bqkv);

  // --- conv stack ---
  conv_enc<<<HW, 64, 0, stream>>>(inp, W_enc, b_enc, feat1);
  im2col3<<<dim3(HW, 9), 64, 0, stream>>>(feat1, A1, 64);
  gemm_bt<<<dim3(64, 4, 1), 256, 0, stream>>>(A1, Btch, feat, b_ch,
      256, 576, 256, /*flags bf16*/2, 0, 0, 0, 0);
  im2col3<<<dim3(HW, 9), 256, 0, stream>>>(feat, A2, 256);
  gemm_bt<<<dim3(64, 12, 1), 256, 0, stream>>>(A2, Btqkv, fqkv, bqkv,
      768, 2304, 768, 0, 0, 0, 0, 0);
  im2col5<<<dim3(HW, 4, 8), dim3(32, 8), 0, stream>>>(feat, Ag);
  gemm_bt<<<dim3(64, 1, 8), 256, 0, stream>>>(Ag, Btoff1, obuf, b_off1,
      32, 800, 256, 0, (long)HW * 800, (long)32 * 800, 32, 32);
  ln_gelu<<<HW, 256, 0, stream>>>(obuf, ln_g, ln_b, ocg);
  gemm_bt<<<dim3(64, 2, 1), 256, 0, stream>>>(ocg, Btoff2, offsb, nullptr,
      98, 256, 98, 0, 0, 0, 0, 0);

  // --- per-query attention path ---
  sampler<<<NQ, 256, 0, stream>>>(coord, fqkv, offsb, inp, attnval, relbuf, vidxb, skipb);
  gemm_bt<<<dim3(64, 4, 1), 256, 0, stream>>>(relbuf, Btc1, hid1, bc1,
      256, 128, 256, /*relu*/1, 0, 0, 0, 0);
  wcoord_softmax<<<NQ, 512, 0, stream>>>(hid1, Wc2, bc2, attnval);
  assemble<<<dim3(NQ, 50), 256, 0, stream>>>(fqkv, attnval, vidxb, cell, featin);
  gemm_bt<<<dim3(64, 4, 1), 256, 0, stream>>>(featin, Wi1p, hid2, bi1,
      256, 12576, 256, /*relu*/1, 0, 0, 0, 0);
  final_out<<<NQ, 256, 0, stream>>>(hid2, Wi2, bi2, skipb, (float*)d_out);
}

// Round 2
// 473.109 us; speedup vs baseline: 1.4115x; 1.4115x over previous
//
#include <hip/hip_runtime.h>
#include <hip/hip_bf16.h>

// ============================================================================
// IDASR pipeline on gfx950 — round 2.
// Changes vs round 1:
//  * big MLP GEMM: fused gather-A (no feat_in materialization) + split-K(8)
//    -> 2048 blocks, partial f32 accumulation + reduce(+bias+relu).
//  * gemm_bt: register-prefetch software pipeline (hide global latency).
//  * wcoord layer2 as GEMM (hid1 bf16) + thin softmax kernel.
// ============================================================================

typedef unsigned short u16;
using frag_ab = __attribute__((ext_vector_type(8))) short;  // 8 x bf16
using frag_cd = __attribute__((ext_vector_type(4))) float;  // 4 x f32 acc

#define HW 4096   // 64*64 spatial
#define NQ 4096   // queries
#define KBIG 12576
#define SPLITK 8

static __device__ __forceinline__ u16 f2b(float f) {
  union { __hip_bfloat16 h; u16 u; } c; c.h = __float2bfloat16(f); return c.u;
}

#define BM 64
#define BN 64
#define BK 32
#define LDSS 40   // lds row stride (elems): 32 + 8 pad

// ---------------------------------------------------------------------------
// Generic bf16 GEMM: C[M,N] = A[M,K] * Bt[N,K]^T (+bias[n]) (+relu) ->f32/bf16
// Register-prefetch pipeline. Batched via z. M % 64 == 0, K % 32 == 0.
// ---------------------------------------------------------------------------
__global__ __launch_bounds__(256)
void gemm_bt(const u16* __restrict__ A, const u16* __restrict__ Bt,
             void* __restrict__ Cv, const float* __restrict__ bias,
             int N, int K, int ldc, int flags,   // flags: 1=relu, 2=bf16 out
             long sA, long sB, long sC, int sBias)
{
  __shared__ u16 As[BM * LDSS];
  __shared__ u16 Bs[BN * LDSS];
  const int z = blockIdx.z;
  A  += (long)z * sA;
  Bt += (long)z * sB;
  const float* bz = bias ? bias + (long)z * sBias : nullptr;

  const int tid  = threadIdx.x;
  const int m0   = blockIdx.x * BM;
  const int n0   = blockIdx.y * BN;
  const int wave = tid >> 6, lane = tid & 63;
  const int mw = (wave & 1) * 32, nw = (wave >> 1) * 32;
  const int lr = lane & 15, lk = lane >> 4;
  const int srow = tid >> 2, scol = (tid & 3) * 8;

  frag_cd acc[2][2] = {};
  const u16* aptr = A + (size_t)(m0 + srow) * K + scol;
  const bool bok  = (n0 + srow) < N;
  const u16* bptr = Bt + (size_t)(n0 + srow) * K + scol;

  uint4 av = *(const uint4*)(aptr);
  uint4 bv = bok ? *(const uint4*)(bptr) : uint4{0u, 0u, 0u, 0u};

  for (int k0 = 0; k0 < K; k0 += BK) {
    *(uint4*)&As[srow * LDSS + scol] = av;
    *(uint4*)&Bs[srow * LDSS + scol] = bv;
    __syncthreads();
    uint4 avn = av, bvn = bv;
    if (k0 + BK < K) {
      avn = *(const uint4*)(aptr + k0 + BK);
      bvn = bok ? *(const uint4*)(bptr + k0 + BK) : uint4{0u, 0u, 0u, 0u};
    }
    frag_ab af0 = *(const frag_ab*)&As[(mw      + lr) * LDSS + lk * 8];
    frag_ab af1 = *(const frag_ab*)&As[(mw + 16 + lr) * LDSS + lk * 8];
    frag_ab bf0 = *(const frag_ab*)&Bs[(nw      + lr) * LDSS + lk * 8];
    frag_ab bf1 = *(const frag_ab*)&Bs[(nw + 16 + lr) * LDSS + lk * 8];
    acc[0][0] = __builtin_amdgcn_mfma_f32_16x16x32_bf16(af0, bf0, acc[0][0], 0, 0, 0);
    acc[0][1] = __builtin_amdgcn_mfma_f32_16x16x32_bf16(af0, bf1, acc[0][1], 0, 0, 0);
    acc[1][0] = __builtin_amdgcn_mfma_f32_16x16x32_bf16(af1, bf0, acc[1][0], 0, 0, 0);
    acc[1][1] = __builtin_amdgcn_mfma_f32_16x16x32_bf16(af1, bf1, acc[1][1], 0, 0, 0);
    __syncthreads();
    av = avn; bv = bvn;
  }

  const bool relu = flags & 1;
  const bool obf  = flags & 2;
  #pragma unroll
  for (int i = 0; i < 2; i++)
    #pragma unroll
    for (int j = 0; j < 2; j++) {
      int col = n0 + nw + j * 16 + lr;        // C/D: col = lane&15
      if (col >= N) continue;
      float badd = bz ? bz[col] : 0.f;
      #pragma unroll
      for (int r = 0; r < 4; r++) {
        int row = m0 + mw + i * 16 + lk * 4 + r;  // C/D: row = (lane>>4)*4+reg
        float v = acc[i][j][r] + badd;
        if (relu) v = fmaxf(v, 0.f);
        size_t idx = (size_t)z * sC + (size_t)row * ldc + col;
        if (obf) ((u16*)Cv)[idx] = f2b(v);
        else     ((float*)Cv)[idx] = v;
      }
    }
}

// ---------------------------------------------------------------------------
// Big MLP GEMM, fused gather-A, split-K.
// A[q][k] built on the fly: j=k>>8 (tap), c=k&255 (channel);
//   j<49 : fqkv_v[vidx[q,j]][c] * attn[q,j,c>>5]   (0 if idx<0)
//   j==49: c==0 -> cell[q,0]*64, c==1 -> cell[q,1]*64, else 0
// Bt = Wi1p (256 x 12576). Output: partial f32 P[z][q][n].
// grid (64, 4, SPLITK), block 256.
// ---------------------------------------------------------------------------
__global__ __launch_bounds__(256)
void gemm_big(const u16* __restrict__ Bt, const float* __restrict__ fqkv,
              const float* __restrict__ attnval, const int* __restrict__ vidx,
              const float* __restrict__ cell, float* __restrict__ P,
              int kchunk)
{
  __shared__ u16 As[BM * LDSS];
  __shared__ u16 Bs[BN * LDSS];
  const int tid  = threadIdx.x;
  const int m0   = blockIdx.x * BM;
  const int n0   = blockIdx.y * BN;
  const int z    = blockIdx.z;
  const int kbeg = z * kchunk;
  const int kend = min(KBIG, kbeg + kchunk);
  const int wave = tid >> 6, lane = tid & 63;
  const int mw = (wave & 1) * 32, nw = (wave >> 1) * 32;
  const int lr = lane & 15, lk = lane >> 4;
  const int srow = tid >> 2, scol = (tid & 3) * 8;
  const int q = m0 + srow;

  frag_cd acc[2][2] = {};
  const u16* bptr = Bt + (size_t)(n0 + srow) * KBIG + scol;

  auto stageA = [&](int k0) -> uint4 {
    const int k = k0 + scol;
    const int j = k >> 8, c = k & 255;
    union { u16 s[8]; uint4 v; } u;
    u.v = uint4{0u, 0u, 0u, 0u};
    if (j < 49) {
      int id = vidx[q * 49 + j];
      if (id >= 0) {
        float w = attnval[((size_t)(q * 49 + j)) * 8 + (c >> 5)];
        const float* src = fqkv + (size_t)id * 768 + 512 + c;
        float4 f0 = *(const float4*)src;
        float4 f1 = *(const float4*)(src + 4);
        u.s[0] = f2b(f0.x * w); u.s[1] = f2b(f0.y * w);
        u.s[2] = f2b(f0.z * w); u.s[3] = f2b(f0.w * w);
        u.s[4] = f2b(f1.x * w); u.s[5] = f2b(f1.y * w);
        u.s[6] = f2b(f1.z * w); u.s[7] = f2b(f1.w * w);
      }
    } else if (c == 0) {
      u.s[0] = f2b(cell[q * 2] * 64.f);
      u.s[1] = f2b(cell[q * 2 + 1] * 64.f);
    }
    return u.v;
  };

  uint4 av = stageA(kbeg);
  uint4 bv = *(const uint4*)(bptr + kbeg);

  for (int k0 = kbeg; k0 < kend; k0 += BK) {
    *(uint4*)&As[srow * LDSS + scol] = av;
    *(uint4*)&Bs[srow * LDSS + scol] = bv;
    __syncthreads();
    uint4 avn = av, bvn = bv;
    if (k0 + BK < kend) {
      avn = stageA(k0 + BK);
      bvn = *(const uint4*)(bptr + k0 + BK);
    }
    frag_ab af0 = *(const frag_ab*)&As[(mw      + lr) * LDSS + lk * 8];
    frag_ab af1 = *(const frag_ab*)&As[(mw + 16 + lr) * LDSS + lk * 8];
    frag_ab bf0 = *(const frag_ab*)&Bs[(nw      + lr) * LDSS + lk * 8];
    frag_ab bf1 = *(const frag_ab*)&Bs[(nw + 16 + lr) * LDSS + lk * 8];
    acc[0][0] = __builtin_amdgcn_mfma_f32_16x16x32_bf16(af0, bf0, acc[0][0], 0, 0, 0);
    acc[0][1] = __builtin_amdgcn_mfma_f32_16x16x32_bf16(af0, bf1, acc[0][1], 0, 0, 0);
    acc[1][0] = __builtin_amdgcn_mfma_f32_16x16x32_bf16(af1, bf0, acc[1][0], 0, 0, 0);
    acc[1][1] = __builtin_amdgcn_mfma_f32_16x16x32_bf16(af1, bf1, acc[1][1], 0, 0, 0);
    __syncthreads();
    av = avn; bv = bvn;
  }

  #pragma unroll
  for (int i = 0; i < 2; i++)
    #pragma unroll
    for (int j = 0; j < 2; j++) {
      int col = n0 + nw + j * 16 + lr;
      #pragma unroll
      for (int r = 0; r < 4; r++) {
        int row = m0 + mw + i * 16 + lk * 4 + r;
        P[(size_t)z * (NQ * 256) + (size_t)row * 256 + col] = acc[i][j][r];
      }
    }
}

// sum split-K partials + bias + relu -> f32
__global__ __launch_bounds__(256)
void reduce_sk(const float* __restrict__ P, float* __restrict__ C,
               const float* __restrict__ bias, int MN, int N, int S)
{
  int i = blockIdx.x * 256 + threadIdx.x;
  if (i >= MN) return;
  float s = 0.f;
  for (int zz = 0; zz < S; zz++) s += P[(size_t)zz * MN + i];
  s += bias[i % N];
  C[i] = fmaxf(s, 0.f);
}

// ---------------------------------------------------------------------------
// Weight packing
// ---------------------------------------------------------------------------
__global__ void pack_conv_w(const float* __restrict__ W, u16* __restrict__ Bt,
                            int O, int Cin, int K2)
{
  int idx = blockIdx.x * 256 + threadIdx.x;
  if (idx >= O * Cin * K2) return;
  int o  = idx / (Cin * K2);
  int r  = idx - o * (Cin * K2);
  int ci = r / K2;
  int s  = r - ci * K2;
  Bt[(size_t)o * (Cin * K2) + s * Cin + ci] = f2b(W[idx]);
}

__global__ void pack_cast(const float* __restrict__ W, u16* __restrict__ Bt,
                          int N, int Kin, int Kout)
{
  int idx = blockIdx.x * 256 + threadIdx.x;
  if (idx >= N * Kout) return;
  int n = idx / Kout, k = idx - n * Kout;
  Bt[idx] = f2b(k < Kin ? W[(size_t)n * Kin + k] : 0.f);
}

__global__ void pack_bias3(const float* __restrict__ a, const float* __restrict__ b,
                           const float* __restrict__ c, float* __restrict__ out)
{
  int i = blockIdx.x * 256 + threadIdx.x;
  if (i < 256) out[i] = a[i];
  else if (i < 512) out[i] = b[i - 256];
  else if (i < 768) out[i] = c[i - 512];
}

// ---------------------------------------------------------------------------
// Encoder conv: 3->64, 3x3 pad1, +bias, relu -> feat1 (HW,64) bf16
// ---------------------------------------------------------------------------
__global__ __launch_bounds__(64)
void conv_enc(const float* __restrict__ inp, const float* __restrict__ W,
              const float* __restrict__ b, u16* __restrict__ feat1)
{
  const int p = blockIdx.x, c = threadIdx.x;
  const int y = p >> 6, x = p & 63;
  float s = b[c];
  #pragma unroll
  for (int ci = 0; ci < 3; ci++)
    #pragma unroll
    for (int dy = 0; dy < 3; dy++) {
      int yy = y + dy - 1;
      if ((unsigned)yy >= 64u) continue;
      #pragma unroll
      for (int dx = 0; dx < 3; dx++) {
        int xx = x + dx - 1;
        if ((unsigned)xx >= 64u) continue;
        s += inp[ci * HW + yy * 64 + xx] * W[((c * 3 + ci) * 3 + dy) * 3 + dx];
      }
    }
  feat1[(size_t)p * 64 + c] = f2b(fmaxf(s, 0.f));
}

__global__ void im2col3(const u16* __restrict__ X, u16* __restrict__ Y, int C)
{
  const int p = blockIdx.x, s = blockIdx.y, c = threadIdx.x;
  const int y = p >> 6, x = p & 63;
  const int yy = y + s / 3 - 1, xx = x + s % 3 - 1;
  u16 v = (((unsigned)yy < 64u) && ((unsigned)xx < 64u))
              ? X[(size_t)(yy * 64 + xx) * C + c] : (u16)0;
  Y[(size_t)p * (9 * C) + s * C + c] = v;
}

__global__ void im2col5(const u16* __restrict__ feat, u16* __restrict__ Yg)
{
  const int p = blockIdx.x, g = blockIdx.z;
  const int s = blockIdx.y * 8 + threadIdx.y;
  if (s >= 25) return;
  const int ci = threadIdx.x;
  const int y = p >> 6, x = p & 63;
  const int yy = y + s / 5 - 2, xx = x + s % 5 - 2;
  u16 v = (((unsigned)yy < 64u) && ((unsigned)xx < 64u))
              ? feat[(size_t)(yy * 64 + xx) * 256 + g * 32 + ci] : (u16)0;
  Yg[((size_t)g * HW + p) * 800 + s * 32 + ci] = v;
}

// ---------------------------------------------------------------------------
// LayerNorm(channel) + exact GELU
// ---------------------------------------------------------------------------
__global__ __launch_bounds__(256)
void ln_gelu(const float* __restrict__ x, const float* __restrict__ g,
             const float* __restrict__ b, u16* __restrict__ y)
{
  const int p = blockIdx.x, c = threadIdx.x;
  __shared__ float r1[4], r2[4];
  float v = x[(size_t)p * 256 + c];
  float s1 = v, s2 = v * v;
  #pragma unroll
  for (int off = 32; off; off >>= 1) {
    s1 += __shfl_xor(s1, off);
    s2 += __shfl_xor(s2, off);
  }
  if ((c & 63) == 0) { r1[c >> 6] = s1; r2[c >> 6] = s2; }
  __syncthreads();
  float t1 = r1[0] + r1[1] + r1[2] + r1[3];
  float t2 = r2[0] + r2[1] + r2[2] + r2[3];
  float mu  = t1 * (1.f / 256.f);
  float var = t2 * (1.f / 256.f) - mu * mu;
  float xn = (v - mu) * rsqrtf(var + 1e-5f) * g[c] + b[c];
  float ge = 0.5f * xn * (1.f + erff(xn * 0.70710678118654752f));
  y[(size_t)p * 256 + c] = f2b(ge);
}

// ---------------------------------------------------------------------------
// Per-query sampler (unchanged from round 1)
// ---------------------------------------------------------------------------
__global__ __launch_bounds__(256)
void sampler(const float* __restrict__ coord, const float* __restrict__ fqkv,
             const float* __restrict__ offs, const float* __restrict__ inp,
             float* __restrict__ attnval, u16* __restrict__ relbuf,
             int* __restrict__ vidx, float* __restrict__ skipb)
{
  const int q = blockIdx.x;
  const int tid = threadIdx.x;
  __shared__ float s_off[98];
  __shared__ int s_idx[49];

  const float c0 = coord[q * 2], c1 = coord[q * 2 + 1];
  const float gxp = ((c1 + 1.f) * 64.f - 1.f) * 0.5f;
  const float gyp = ((c0 + 1.f) * 64.f - 1.f) * 0.5f;
  const int ixn = (int)rintf(gxp), iyn = (int)rintf(gyp);
  const bool inn = ((unsigned)ixn < 64u) && ((unsigned)iyn < 64u);

  if (tid < 98) {
    float v = inn ? offs[(size_t)(iyn * 64 + ixn) * 98 + tid] : 0.f;
    s_off[tid] = tanhf(v) * (2.f / 63.f);
  }
  __syncthreads();

  const float scky = inn ? (-1.f + (float)(2 * iyn + 1) * (1.f / 64.f)) : 0.f;
  const float sckx = inn ? (-1.f + (float)(2 * ixn + 1) * (1.f / 64.f)) : 0.f;

  if (tid < 49) {
    const int a = tid / 7, bb = tid - a * 7;
    float sy = scky + (float)(a - 3) * (2.f / 64.f) + s_off[2 * tid];
    float sx = sckx + (float)(bb - 3) * (2.f / 64.f) + s_off[2 * tid + 1];
    relbuf[(size_t)q * 128 + 2 * tid]     = f2b((c0 - sy) * 64.f);
    relbuf[(size_t)q * 128 + 2 * tid + 1] = f2b((c1 - sx) * 64.f);
    float gx2 = ((sx + 1.f) * 64.f - 1.f) * 0.5f;
    float gy2 = ((sy + 1.f) * 64.f - 1.f) * 0.5f;
    int ix2 = (int)rintf(gx2), iy2 = (int)rintf(gy2);
    int id = (((unsigned)ix2 < 64u) && ((unsigned)iy2 < 64u)) ? (iy2 * 64 + ix2) : -1;
    s_idx[tid] = id;
    vidx[q * 49 + tid] = id;
  } else if (tid >= 98 && tid < 128) {
    relbuf[(size_t)q * 128 + tid] = 0;
  }
  __syncthreads();

  const float x0f = floorf(gxp), y0f = floorf(gyp);
  const float wx = gxp - x0f, wy = gyp - y0f;
  const int x0 = (int)x0f, y0 = (int)y0f;
  float qc = 0.f;
  #pragma unroll
  for (int t = 0; t < 4; t++) {
    int xi = x0 + (t & 1), yi = y0 + (t >> 1);
    if (((unsigned)xi < 64u) && ((unsigned)yi < 64u)) {
      float w = ((t & 1) ? wx : 1.f - wx) * ((t >> 1) ? wy : 1.f - wy);
      qc += w * fqkv[(size_t)(yi * 64 + xi) * 768 + tid];
    }
  }
  qc *= 0.17677669529663687f;  // 1/sqrt(32)

  const int h = tid >> 5;
  for (int k = 0; k < 49; k++) {
    int id = s_idx[k];
    float kv = (id >= 0) ? fqkv[(size_t)id * 768 + 256 + tid] : 0.f;
    float p = qc * kv;
    p += __shfl_down(p, 16, 32);
    p += __shfl_down(p, 8, 32);
    p += __shfl_down(p, 4, 32);
    p += __shfl_down(p, 2, 32);
    p += __shfl_down(p, 1, 32);
    if ((tid & 31) == 0) attnval[((size_t)q * 49 + k) * 8 + h] = p;
  }

  if (tid < 3) {
    float gx = fminf(fmaxf(gxp, 0.f), 63.f);
    float gy = fminf(fmaxf(gyp, 0.f), 63.f);
    float xf = floorf(gx), yf = floorf(gy);
    float wxs = gx - xf, wys = gy - yf;
    int xa = (int)xf, ya = (int)yf;
    int xb = min(xa + 1, 63), yb = min(ya + 1, 63);
    const float* ch = inp + tid * HW;
    float v = (1.f - wxs) * (1.f - wys) * ch[ya * 64 + xa]
            + wxs * (1.f - wys) * ch[ya * 64 + xb]
            + (1.f - wxs) * wys * ch[yb * 64 + xa]
            + wxs * wys * ch[yb * 64 + xb];
    skipb[q * 3 + tid] = v;
  }
}

// ---------------------------------------------------------------------------
// softmax over 49 taps per head; wc (Q,49) logit bias from coord-MLP GEMM.
// block 512 (8 waves = 8 heads), grid NQ. attnval updated in-place.
// ---------------------------------------------------------------------------
__global__ __launch_bounds__(512)
void softmax_k(const float* __restrict__ wc, float* __restrict__ attnval)
{
  const int q = blockIdx.x;
  const int tid = threadIdx.x;
  const int hh = tid >> 6, l = tid & 63;
  float v = (l < 49) ? wc[(size_t)q * 49 + l] + attnval[((size_t)q * 49 + l) * 8 + hh]
                     : -1e30f;
  float m = v;
  #pragma unroll
  for (int off = 32; off; off >>= 1) m = fmaxf(m, __shfl_xor(m, off));
  float e = (l < 49) ? expf(v - m) : 0.f;
  float s = e;
  #pragma unroll
  for (int off = 32; off; off >>= 1) s += __shfl_xor(s, off);
  if (l < 49) attnval[((size_t)q * 49 + l) * 8 + hh] = e / s;
}

// ---------------------------------------------------------------------------
// Final: pred = hid2 @ Wi2^T + bi2 + skip. block 256, grid NQ.
// ---------------------------------------------------------------------------
__global__ __launch_bounds__(256)
void final_out(const float* __restrict__ hid2, const float* __restrict__ Wi2,
               const float* __restrict__ bi2, const float* __restrict__ skipb,
               float* __restrict__ out)
{
  const int q = blockIdx.x, c = threadIdx.x;
  __shared__ float part[3][4];
  float hv = hid2[(size_t)q * 256 + c];
  float p0 = hv * Wi2[c], p1 = hv * Wi2[256 + c], p2 = hv * Wi2[512 + c];
  #pragma unroll
  for (int off = 32; off; off >>= 1) {
    p0 += __shfl_xor(p0, off);
    p1 += __shfl_xor(p1, off);
    p2 += __shfl_xor(p2, off);
  }
  if ((c & 63) == 0) {
    int w = c >> 6;
    part[0][w] = p0; part[1][w] = p1; part[2][w] = p2;
  }
  __syncthreads();
  if (c < 3)
    out[q * 3 + c] = bi2[c] + skipb[q * 3 + c]
                   + part[c][0] + part[c][1] + part[c][2] + part[c][3];
}

// ===========================================================================
extern "C" void kernel_launch(void* const* d_in, const int* in_sizes, int n_in,
                              void* d_out, int out_size, void* d_ws, size_t ws_size,
                              hipStream_t stream)
{
  const float* inp    = (const float*)d_in[0];
  const float* coord  = (const float*)d_in[1];
  const float* cell   = (const float*)d_in[2];
  const float* W_enc  = (const float*)d_in[3];
  const float* b_enc  = (const float*)d_in[4];
  const float* W_ch   = (const float*)d_in[5];
  const float* b_ch   = (const float*)d_in[6];
  const float* W_q    = (const float*)d_in[7];
  const float* b_q    = (const float*)d_in[8];
  const float* W_k    = (const float*)d_in[9];
  const float* b_k    = (const float*)d_in[10];
  const float* W_v    = (const float*)d_in[11];
  const float* b_v    = (const float*)d_in[12];
  const float* W_off1 = (const float*)d_in[13];
  const float* b_off1 = (const float*)d_in[14];
  const float* ln_g   = (const float*)d_in[15];
  const float* ln_b   = (const float*)d_in[16];
  const float* W_off2 = (const float*)d_in[17];
  const float* Wc1    = (const float*)d_in[18];
  const float* bc1    = (const float*)d_in[19];
  const float* Wc2    = (const float*)d_in[20];
  const float* bc2    = (const float*)d_in[21];
  const float* Wi1    = (const float*)d_in[22];
  const float* bi1    = (const float*)d_in[23];
  const float* Wi2    = (const float*)d_in[24];
  const float* bi2    = (const float*)d_in[25];

  char* base = (char*)d_ws;
  size_t off = 0;
  auto alloc = [&](size_t bytes) -> char* {
    char* r = base + off;
    off = (off + bytes + 255) & ~(size_t)255;
    return r;
  };

  // --- scratch region (dead before gemm_big runs) ---
  u16*   A2     = (u16*)  alloc((size_t)HW * 2304 * 2);
  u16*   Ag     = (u16*)  alloc((size_t)8 * HW * 800 * 2);
  float* obuf   = (float*)alloc((size_t)HW * 256 * 4);
  u16*   ocg    = (u16*)  alloc((size_t)HW * 256 * 2);
  float* offsb  = (float*)alloc((size_t)HW * 98 * 4);
  u16*   feat1  = (u16*)  alloc((size_t)HW * 64 * 2);
  u16*   A1     = (u16*)  alloc((size_t)HW * 576 * 2);
  u16*   feat   = (u16*)  alloc((size_t)HW * 256 * 2);
  u16*   hid1   = (u16*)  alloc((size_t)NQ * 256 * 2);
  float* wcb    = (float*)alloc((size_t)NQ * 49 * 4);
  u16*   relbuf = (u16*)  alloc((size_t)NQ * 128 * 2);
  u16*   Btqkv  = (u16*)  alloc((size_t)768 * 2304 * 2);
  u16*   Btch   = (u16*)  alloc((size_t)256 * 576 * 2);
  u16*   Btoff1 = (u16*)  alloc((size_t)256 * 800 * 2);
  u16*   Btoff2 = (u16*)  alloc((size_t)98 * 256 * 2);
  u16*   Btc1   = (u16*)  alloc((size_t)256 * 128 * 2);
  u16*   Btc2   = (u16*)  alloc((size_t)49 * 256 * 2);
  // split-K partials alias the (dead by then) scratch region: 8 x 4 MB = 33.5 MB
  float* Pbuf   = (float*)base;
  // --- persistent buffers ---
  float* fqkv    = (float*)alloc((size_t)HW * 768 * 4);
  float* attnval = (float*)alloc((size_t)NQ * 49 * 8 * 4);
  int*   vidxb   = (int*)  alloc((size_t)NQ * 49 * 4);
  float* skipb   = (float*)alloc((size_t)NQ * 3 * 4);
  float* hid2    = (float*)alloc((size_t)NQ * 256 * 4);
  u16*   Wi1p    = (u16*)  alloc((size_t)256 * KBIG * 2);
  float* bqkv    = (float*)alloc(768 * 4);
  (void)ws_size; (void)in_sizes; (void)n_in; (void)out_size;

  // --- weight packing ---
  pack_conv_w<<<(256 * 64 * 9 + 255) / 256, 256, 0, stream>>>(W_ch, Btch, 256, 64, 9);
  pack_conv_w<<<(256 * 256 * 9 + 255) / 256, 256, 0, stream>>>(W_q, Btqkv, 256, 256, 9);
  pack_conv_w<<<(256 * 256 * 9 + 255) / 256, 256, 0, stream>>>(W_k, Btqkv + (size_t)256 * 2304, 256, 256, 9);
  pack_conv_w<<<(256 * 256 * 9 + 255) / 256, 256, 0, stream>>>(W_v, Btqkv + (size_t)512 * 2304, 256, 256, 9);
  pack_conv_w<<<(256 * 32 * 25 + 255) / 256, 256, 0, stream>>>(W_off1, Btoff1, 256, 32, 25);
  pack_cast<<<(98 * 256 + 255) / 256, 256, 0, stream>>>(W_off2, Btoff2, 98, 256, 256);
  pack_cast<<<(256 * 128 + 255) / 256, 256, 0, stream>>>(Wc1, Btc1, 256, 98, 128);
  pack_cast<<<(49 * 256 + 255) / 256, 256, 0, stream>>>(Wc2, Btc2, 49, 256, 256);
  pack_cast<<<(256 * KBIG + 255) / 256, 256, 0, stream>>>(Wi1, Wi1p, 256, 12546, KBIG);
  pack_bias3<<<3, 256, 0, stream>>>(b_q, b_k, b_v, bqkv);

  // --- conv stack ---
  conv_enc<<<HW, 64, 0, stream>>>(inp, W_enc, b_enc, feat1);
  im2col3<<<dim3(HW, 9), 64, 0, stream>>>(feat1, A1, 64);
  gemm_bt<<<dim3(64, 4, 1), 256, 0, stream>>>(A1, Btch, feat, b_ch,
      256, 576, 256, /*bf16*/2, 0, 0, 0, 0);
  im2col3<<<dim3(HW, 9), 256, 0, stream>>>(feat, A2, 256);
  gemm_bt<<<dim3(64, 12, 1), 256, 0, stream>>>(A2, Btqkv, fqkv, bqkv,
      768, 2304, 768, 0, 0, 0, 0, 0);
  im2col5<<<dim3(HW, 4, 8), dim3(32, 8), 0, stream>>>(feat, Ag);
  gemm_bt<<<dim3(64, 1, 8), 256, 0, stream>>>(Ag, Btoff1, obuf, b_off1,
      32, 800, 256, 0, (long)HW * 800, (long)32 * 800, 32, 32);
  ln_gelu<<<HW, 256, 0, stream>>>(obuf, ln_g, ln_b, ocg);
  gemm_bt<<<dim3(64, 2, 1), 256, 0, stream>>>(ocg, Btoff2, offsb, nullptr,
      98, 256, 98, 0, 0, 0, 0, 0);

  // --- per-query attention path ---
  sampler<<<NQ, 256, 0, stream>>>(coord, fqkv, offsb, inp, attnval, relbuf, vidxb, skipb);
  gemm_bt<<<dim3(64, 4, 1), 256, 0, stream>>>(relbuf, Btc1, hid1, bc1,
      256, 128, 256, /*relu+bf16*/3, 0, 0, 0, 0);
  gemm_bt<<<dim3(64, 1, 1), 256, 0, stream>>>(hid1, Btc2, wcb, bc2,
      49, 256, 49, 0, 0, 0, 0, 0);
  softmax_k<<<NQ, 512, 0, stream>>>(wcb, attnval);

  // --- big MLP: fused gather-A + split-K ---
  const int kchunk = ((KBIG / BK + SPLITK - 1) / SPLITK) * BK;  // 1600
  gemm_big<<<dim3(64, 4, SPLITK), 256, 0, stream>>>(
      Wi1p, fqkv, attnval, vidxb, cell, Pbuf, kchunk);
  reduce_sk<<<(NQ * 256 + 255) / 256, 256, 0, stream>>>(
      Pbuf, hid2, bi1, NQ * 256, 256, SPLITK);
  final_out<<<NQ, 256, 0, stream>>>(hid2, Wi2, bi2, skipb, (float*)d_out);
}

// Round 3
// 382.187 us; speedup vs baseline: 1.7473x; 1.2379x over previous
//
#include <hip/hip_runtime.h>
#include <hip/hip_bf16.h>

// ============================================================================
// IDASR pipeline on gfx950 — round 3.
// Changes vs round 2:
//  * gemm_big: BN=128 (grid 64x2x8) — halves gather redundancy, doubles
//    MFMA per staged tile, packed bf16 conversion.
//  * implicit-im2col gemm_conv<W3,SH,PAD> for ch/qkv/off1 convs — removes
//    im2col3 x2 (36864 blocks each), im2col5 (131072 blocks), A1/A2/Ag bufs.
//  * pack_misc: one launch for all small weight packs.
// ============================================================================

typedef unsigned short u16;
typedef unsigned int u32;
using frag_ab = __attribute__((ext_vector_type(8))) short;  // 8 x bf16
using frag_cd = __attribute__((ext_vector_type(4))) float;  // 4 x f32 acc

#define HW 4096
#define NQ 4096
#define KBIG 12576
#define SPLITK 8

static __device__ __forceinline__ u16 f2b(float f) {
  union { __hip_bfloat16 h; u16 u; } c; c.h = __float2bfloat16(f); return c.u;
}
static __device__ __forceinline__ u32 pk2(float a, float b) {
  union { __hip_bfloat162 h; u32 u; } c;
  c.h = __float22bfloat162_rn(float2{a, b});
  return c.u;
}

#define BM 64
#define BN 64
#define BK 32
#define LDSS 40   // lds row stride (elems): 32 + 8 pad

// ---------------------------------------------------------------------------
// Generic bf16 GEMM: C[M,N] = A[M,K] * Bt[N,K]^T (+bias) (+relu) -> f32/bf16
// Register-prefetch pipeline. Used for 1x1-conv / dense layers.
// ---------------------------------------------------------------------------
__global__ __launch_bounds__(256)
void gemm_bt(const u16* __restrict__ A, const u16* __restrict__ Bt,
             void* __restrict__ Cv, const float* __restrict__ bias,
             int N, int K, int ldc, int flags,   // 1=relu, 2=bf16 out
             long sA, long sB, long sC, int sBias)
{
  __shared__ u16 As[BM * LDSS];
  __shared__ u16 Bs[BN * LDSS];
  const int z = blockIdx.z;
  A  += (long)z * sA;
  Bt += (long)z * sB;
  const float* bz = bias ? bias + (long)z * sBias : nullptr;

  const int tid  = threadIdx.x;
  const int m0   = blockIdx.x * BM;
  const int n0   = blockIdx.y * BN;
  const int wave = tid >> 6, lane = tid & 63;
  const int mw = (wave & 1) * 32, nw = (wave >> 1) * 32;
  const int lr = lane & 15, lk = lane >> 4;
  const int srow = tid >> 2, scol = (tid & 3) * 8;

  frag_cd acc[2][2] = {};
  const u16* aptr = A + (size_t)(m0 + srow) * K + scol;
  const bool bok  = (n0 + srow) < N;
  const u16* bptr = Bt + (size_t)(n0 + srow) * K + scol;

  uint4 av = *(const uint4*)(aptr);
  uint4 bv = bok ? *(const uint4*)(bptr) : uint4{0u, 0u, 0u, 0u};

  for (int k0 = 0; k0 < K; k0 += BK) {
    *(uint4*)&As[srow * LDSS + scol] = av;
    *(uint4*)&Bs[srow * LDSS + scol] = bv;
    __syncthreads();
    uint4 avn = av, bvn = bv;
    if (k0 + BK < K) {
      avn = *(const uint4*)(aptr + k0 + BK);
      bvn = bok ? *(const uint4*)(bptr + k0 + BK) : uint4{0u, 0u, 0u, 0u};
    }
    frag_ab af0 = *(const frag_ab*)&As[(mw      + lr) * LDSS + lk * 8];
    frag_ab af1 = *(const frag_ab*)&As[(mw + 16 + lr) * LDSS + lk * 8];
    frag_ab bf0 = *(const frag_ab*)&Bs[(nw      + lr) * LDSS + lk * 8];
    frag_ab bf1 = *(const frag_ab*)&Bs[(nw + 16 + lr) * LDSS + lk * 8];
    acc[0][0] = __builtin_amdgcn_mfma_f32_16x16x32_bf16(af0, bf0, acc[0][0], 0, 0, 0);
    acc[0][1] = __builtin_amdgcn_mfma_f32_16x16x32_bf16(af0, bf1, acc[0][1], 0, 0, 0);
    acc[1][0] = __builtin_amdgcn_mfma_f32_16x16x32_bf16(af1, bf0, acc[1][0], 0, 0, 0);
    acc[1][1] = __builtin_amdgcn_mfma_f32_16x16x32_bf16(af1, bf1, acc[1][1], 0, 0, 0);
    __syncthreads();
    av = avn; bv = bvn;
  }

  const bool relu = flags & 1;
  const bool obf  = flags & 2;
  #pragma unroll
  for (int i = 0; i < 2; i++)
    #pragma unroll
    for (int j = 0; j < 2; j++) {
      int col = n0 + nw + j * 16 + lr;
      if (col >= N) continue;
      float badd = bz ? bz[col] : 0.f;
      #pragma unroll
      for (int r = 0; r < 4; r++) {
        int row = m0 + mw + i * 16 + lk * 4 + r;
        float v = acc[i][j][r] + badd;
        if (relu) v = fmaxf(v, 0.f);
        size_t idx = (size_t)z * sC + (size_t)row * ldc + col;
        if (obf) ((u16*)Cv)[idx] = f2b(v);
        else     ((float*)Cv)[idx] = v;
      }
    }
}

// ---------------------------------------------------------------------------
// Implicit-im2col conv GEMM. A row p (spatial), k = s*C + c, s = dy*W3+dx.
// A staged directly from feat (FC channels, cb = z*cbStride for groups).
// ---------------------------------------------------------------------------
template<int W3, int SH, int PAD>
__global__ __launch_bounds__(256)
void gemm_conv(const u16* __restrict__ feat, const u16* __restrict__ Bt,
               void* __restrict__ Cv, const float* __restrict__ bias,
               int N, int K, int ldc, int flags, int FC, int cbStride,
               long sB, long sC, int sBias)
{
  __shared__ u16 As[BM * LDSS];
  __shared__ u16 Bs[BN * LDSS];
  const int z = blockIdx.z;
  Bt += (long)z * sB;
  const float* bz = bias ? bias + (long)z * sBias : nullptr;
  const int cb = z * cbStride;

  const int tid  = threadIdx.x;
  const int m0   = blockIdx.x * BM;
  const int n0   = blockIdx.y * BN;
  const int wave = tid >> 6, lane = tid & 63;
  const int mw = (wave & 1) * 32, nw = (wave >> 1) * 32;
  const int lr = lane & 15, lk = lane >> 4;
  const int srow = tid >> 2, scol = (tid & 3) * 8;
  const int p = m0 + srow, y = p >> 6, x = p & 63;

  frag_cd acc[2][2] = {};
  const bool bok  = (n0 + srow) < N;
  const u16* bptr = Bt + (size_t)(n0 + srow) * K + scol;

  auto stageA = [&](int k0) -> uint4 {
    int k = k0 + scol;
    int s = k >> SH;
    int c = k & ((1 << SH) - 1);
    int dy = s / W3, dx = s - dy * W3;
    int yy = y + dy - PAD, xx = x + dx - PAD;
    if (((unsigned)yy < 64u) && ((unsigned)xx < 64u))
      return *(const uint4*)&feat[(size_t)(yy * 64 + xx) * FC + cb + c];
    return uint4{0u, 0u, 0u, 0u};
  };

  uint4 av = stageA(0);
  uint4 bv = bok ? *(const uint4*)(bptr) : uint4{0u, 0u, 0u, 0u};

  for (int k0 = 0; k0 < K; k0 += BK) {
    *(uint4*)&As[srow * LDSS + scol] = av;
    *(uint4*)&Bs[srow * LDSS + scol] = bv;
    __syncthreads();
    uint4 avn = av, bvn = bv;
    if (k0 + BK < K) {
      avn = stageA(k0 + BK);
      bvn = bok ? *(const uint4*)(bptr + k0 + BK) : uint4{0u, 0u, 0u, 0u};
    }
    frag_ab af0 = *(const frag_ab*)&As[(mw      + lr) * LDSS + lk * 8];
    frag_ab af1 = *(const frag_ab*)&As[(mw + 16 + lr) * LDSS + lk * 8];
    frag_ab bf0 = *(const frag_ab*)&Bs[(nw      + lr) * LDSS + lk * 8];
    frag_ab bf1 = *(const frag_ab*)&Bs[(nw + 16 + lr) * LDSS + lk * 8];
    acc[0][0] = __builtin_amdgcn_mfma_f32_16x16x32_bf16(af0, bf0, acc[0][0], 0, 0, 0);
    acc[0][1] = __builtin_amdgcn_mfma_f32_16x16x32_bf16(af0, bf1, acc[0][1], 0, 0, 0);
    acc[1][0] = __builtin_amdgcn_mfma_f32_16x16x32_bf16(af1, bf0, acc[1][0], 0, 0, 0);
    acc[1][1] = __builtin_amdgcn_mfma_f32_16x16x32_bf16(af1, bf1, acc[1][1], 0, 0, 0);
    __syncthreads();
    av = avn; bv = bvn;
  }

  const bool relu = flags & 1;
  const bool obf  = flags & 2;
  #pragma unroll
  for (int i = 0; i < 2; i++)
    #pragma unroll
    for (int j = 0; j < 2; j++) {
      int col = n0 + nw + j * 16 + lr;
      if (col >= N) continue;
      float badd = bz ? bz[col] : 0.f;
      #pragma unroll
      for (int r = 0; r < 4; r++) {
        int row = m0 + mw + i * 16 + lk * 4 + r;
        float v = acc[i][j][r] + badd;
        if (relu) v = fmaxf(v, 0.f);
        size_t idx = (size_t)z * sC + (size_t)row * ldc + col;
        if (obf) ((u16*)Cv)[idx] = f2b(v);
        else     ((float*)Cv)[idx] = v;
      }
    }
}

// ---------------------------------------------------------------------------
// Big MLP GEMM, fused gather-A, split-K. Tile 64x128, grid (64, 2, SPLITK).
// A[q][k]: j=k>>8 (tap), c=k&255: fqkv_v[vidx[q,j]][c] * attn[q,j,c>>5].
// ---------------------------------------------------------------------------
__global__ __launch_bounds__(256)
void gemm_big(const u16* __restrict__ Bt, const float* __restrict__ fqkv,
              const float* __restrict__ attnval, const int* __restrict__ vidx,
              const float* __restrict__ cell, float* __restrict__ P,
              int kchunk)
{
  __shared__ u16 As[64 * LDSS];
  __shared__ u16 Bs[128 * LDSS];
  const int tid  = threadIdx.x;
  const int m0   = blockIdx.x * 64;
  const int n0   = blockIdx.y * 128;
  const int z    = blockIdx.z;
  const int kbeg = z * kchunk;
  const int kend = min(KBIG, kbeg + kchunk);
  const int wave = tid >> 6, lane = tid & 63;
  const int mw = (wave & 1) * 32, nwv = (wave >> 1) * 64;
  const int lr = lane & 15, lk = lane >> 4;
  const int srow = tid >> 2, scol = (tid & 3) * 8;
  const int q = m0 + srow;

  frag_cd acc[2][4] = {};
  const u16* bptr0 = Bt + (size_t)(n0 + srow) * KBIG + scol;
  const u16* bptr1 = bptr0 + (size_t)64 * KBIG;

  auto stageA = [&](int k0) -> uint4 {
    const int k = k0 + scol;
    const int j = k >> 8, c = k & 255;
    union { u32 w[4]; uint4 v; } u;
    u.v = uint4{0u, 0u, 0u, 0u};
    if (j < 49) {
      int id = vidx[q * 49 + j];
      if (id >= 0) {
        float w = attnval[((size_t)(q * 49 + j)) * 8 + (c >> 5)];
        const float* src = fqkv + (size_t)id * 768 + 512 + c;
        float4 f0 = *(const float4*)src;
        float4 f1 = *(const float4*)(src + 4);
        u.w[0] = pk2(f0.x * w, f0.y * w);
        u.w[1] = pk2(f0.z * w, f0.w * w);
        u.w[2] = pk2(f1.x * w, f1.y * w);
        u.w[3] = pk2(f1.z * w, f1.w * w);
      }
    } else if (c == 0) {
      u.w[0] = pk2(cell[q * 2] * 64.f, cell[q * 2 + 1] * 64.f);
    }
    return u.v;
  };

  uint4 av  = stageA(kbeg);
  uint4 bv0 = *(const uint4*)(bptr0 + kbeg);
  uint4 bv1 = *(const uint4*)(bptr1 + kbeg);

  for (int k0 = kbeg; k0 < kend; k0 += BK) {
    *(uint4*)&As[srow * LDSS + scol] = av;
    *(uint4*)&Bs[srow * LDSS + scol] = bv0;
    *(uint4*)&Bs[(srow + 64) * LDSS + scol] = bv1;
    __syncthreads();
    uint4 avn = av, bv0n = bv0, bv1n = bv1;
    if (k0 + BK < kend) {
      avn  = stageA(k0 + BK);
      bv0n = *(const uint4*)(bptr0 + k0 + BK);
      bv1n = *(const uint4*)(bptr1 + k0 + BK);
    }
    frag_ab af0 = *(const frag_ab*)&As[(mw      + lr) * LDSS + lk * 8];
    frag_ab af1 = *(const frag_ab*)&As[(mw + 16 + lr) * LDSS + lk * 8];
    #pragma unroll
    for (int j = 0; j < 4; j++) {
      frag_ab bf = *(const frag_ab*)&Bs[(nwv + j * 16 + lr) * LDSS + lk * 8];
      acc[0][j] = __builtin_amdgcn_mfma_f32_16x16x32_bf16(af0, bf, acc[0][j], 0, 0, 0);
      acc[1][j] = __builtin_amdgcn_mfma_f32_16x16x32_bf16(af1, bf, acc[1][j], 0, 0, 0);
    }
    __syncthreads();
    av = avn; bv0 = bv0n; bv1 = bv1n;
  }

  #pragma unroll
  for (int i = 0; i < 2; i++)
    #pragma unroll
    for (int j = 0; j < 4; j++) {
      int col = n0 + nwv + j * 16 + lr;
      #pragma unroll
      for (int r = 0; r < 4; r++) {
        int row = m0 + mw + i * 16 + lk * 4 + r;
        P[(size_t)z * (NQ * 256) + (size_t)row * 256 + col] = acc[i][j][r];
      }
    }
}

// sum split-K partials + bias + relu -> f32
__global__ __launch_bounds__(256)
void reduce_sk(const float* __restrict__ P, float* __restrict__ C,
               const float* __restrict__ bias, int MN, int N, int S)
{
  int i = blockIdx.x * 256 + threadIdx.x;
  if (i >= MN) return;
  float s = 0.f;
  for (int zz = 0; zz < S; zz++) s += P[(size_t)zz * MN + i];
  s += bias[i % N];
  C[i] = fmaxf(s, 0.f);
}

// ---------------------------------------------------------------------------
// Weight packing — one launch for all small weights.
// ---------------------------------------------------------------------------
static __device__ __forceinline__
void packconv(const float* __restrict__ W, u16* __restrict__ Bt,
              int Cin, int K2, int idx)
{
  int o  = idx / (Cin * K2);
  int r  = idx - o * (Cin * K2);
  int ci = r / K2;
  int s  = r - ci * K2;
  Bt[(size_t)o * (Cin * K2) + s * Cin + ci] = f2b(W[idx]);
}
static __device__ __forceinline__
void packcast(const float* __restrict__ W, u16* __restrict__ Bt,
              int Kin, int Kout, int idx)
{
  int n = idx / Kout, k = idx - n * Kout;
  Bt[idx] = f2b(k < Kin ? W[(size_t)n * Kin + k] : 0.f);
}

#define SZ_CH   147456   // 256*64*9
#define SZ_QKV  589824   // 256*256*9
#define SZ_OFF1 204800   // 256*32*25
#define SZ_OFF2 25088    // 98*256
#define SZ_C1   32768    // 256*128
#define SZ_C2   12544    // 49*256
#define SZ_PACK (SZ_CH + 3*SZ_QKV + SZ_OFF1 + SZ_OFF2 + SZ_C1 + SZ_C2 + 768)

__global__ void pack_misc(const float* W_ch, const float* W_q, const float* W_k,
                          const float* W_v, const float* W_off1, const float* W_off2,
                          const float* Wc1, const float* Wc2,
                          const float* b_q, const float* b_k, const float* b_v,
                          u16* Btch, u16* Btqkv, u16* Btoff1, u16* Btoff2,
                          u16* Btc1, u16* Btc2, float* bqkv)
{
  int i = blockIdx.x * 256 + threadIdx.x;
  if (i < SZ_CH) { packconv(W_ch, Btch, 64, 9, i); return; }
  i -= SZ_CH;
  if (i < SZ_QKV) { packconv(W_q, Btqkv, 256, 9, i); return; }
  i -= SZ_QKV;
  if (i < SZ_QKV) { packconv(W_k, Btqkv + (size_t)256 * 2304, 256, 9, i); return; }
  i -= SZ_QKV;
  if (i < SZ_QKV) { packconv(W_v, Btqkv + (size_t)512 * 2304, 256, 9, i); return; }
  i -= SZ_QKV;
  if (i < SZ_OFF1) { packconv(W_off1, Btoff1, 32, 25, i); return; }
  i -= SZ_OFF1;
  if (i < SZ_OFF2) { packcast(W_off2, Btoff2, 256, 256, i); return; }
  i -= SZ_OFF2;
  if (i < SZ_C1) { packcast(Wc1, Btc1, 98, 128, i); return; }
  i -= SZ_C1;
  if (i < SZ_C2) { packcast(Wc2, Btc2, 256, 256, i); return; }
  i -= SZ_C2;
  if (i < 768) {
    bqkv[i] = (i < 256) ? b_q[i] : (i < 512) ? b_k[i - 256] : b_v[i - 512];
  }
}

__global__ void pack_cast(const float* __restrict__ W, u16* __restrict__ Bt,
                          int N, int Kin, int Kout)
{
  int idx = blockIdx.x * 256 + threadIdx.x;
  if (idx >= N * Kout) return;
  int n = idx / Kout, k = idx - n * Kout;
  Bt[idx] = f2b(k < Kin ? W[(size_t)n * Kin + k] : 0.f);
}

// ---------------------------------------------------------------------------
// Encoder conv: 3->64, 3x3 pad1, +bias, relu -> feat1 (HW,64) bf16
// ---------------------------------------------------------------------------
__global__ __launch_bounds__(64)
void conv_enc(const float* __restrict__ inp, const float* __restrict__ W,
              const float* __restrict__ b, u16* __restrict__ feat1)
{
  const int p = blockIdx.x, c = threadIdx.x;
  const int y = p >> 6, x = p & 63;
  float s = b[c];
  #pragma unroll
  for (int ci = 0; ci < 3; ci++)
    #pragma unroll
    for (int dy = 0; dy < 3; dy++) {
      int yy = y + dy - 1;
      if ((unsigned)yy >= 64u) continue;
      #pragma unroll
      for (int dx = 0; dx < 3; dx++) {
        int xx = x + dx - 1;
        if ((unsigned)xx >= 64u) continue;
        s += inp[ci * HW + yy * 64 + xx] * W[((c * 3 + ci) * 3 + dy) * 3 + dx];
      }
    }
  feat1[(size_t)p * 64 + c] = f2b(fmaxf(s, 0.f));
}

// ---------------------------------------------------------------------------
// LayerNorm(channel) + exact GELU
// ---------------------------------------------------------------------------
__global__ __launch_bounds__(256)
void ln_gelu(const float* __restrict__ x, const float* __restrict__ g,
             const float* __restrict__ b, u16* __restrict__ y)
{
  const int p = blockIdx.x, c = threadIdx.x;
  __shared__ float r1[4], r2[4];
  float v = x[(size_t)p * 256 + c];
  float s1 = v, s2 = v * v;
  #pragma unroll
  for (int off = 32; off; off >>= 1) {
    s1 += __shfl_xor(s1, off);
    s2 += __shfl_xor(s2, off);
  }
  if ((c & 63) == 0) { r1[c >> 6] = s1; r2[c >> 6] = s2; }
  __syncthreads();
  float t1 = r1[0] + r1[1] + r1[2] + r1[3];
  float t2 = r2[0] + r2[1] + r2[2] + r2[3];
  float mu  = t1 * (1.f / 256.f);
  float var = t2 * (1.f / 256.f) - mu * mu;
  float xn = (v - mu) * rsqrtf(var + 1e-5f) * g[c] + b[c];
  float ge = 0.5f * xn * (1.f + erff(xn * 0.70710678118654752f));
  y[(size_t)p * 256 + c] = f2b(ge);
}

// ---------------------------------------------------------------------------
// Per-query sampler
// ---------------------------------------------------------------------------
__global__ __launch_bounds__(256)
void sampler(const float* __restrict__ coord, const float* __restrict__ fqkv,
             const float* __restrict__ offs, const float* __restrict__ inp,
             float* __restrict__ attnval, u16* __restrict__ relbuf,
             int* __restrict__ vidx, float* __restrict__ skipb)
{
  const int q = blockIdx.x;
  const int tid = threadIdx.x;
  __shared__ float s_off[98];
  __shared__ int s_idx[49];

  const float c0 = coord[q * 2], c1 = coord[q * 2 + 1];
  const float gxp = ((c1 + 1.f) * 64.f - 1.f) * 0.5f;
  const float gyp = ((c0 + 1.f) * 64.f - 1.f) * 0.5f;
  const int ixn = (int)rintf(gxp), iyn = (int)rintf(gyp);
  const bool inn = ((unsigned)ixn < 64u) && ((unsigned)iyn < 64u);

  if (tid < 98) {
    float v = inn ? offs[(size_t)(iyn * 64 + ixn) * 98 + tid] : 0.f;
    s_off[tid] = tanhf(v) * (2.f / 63.f);
  }
  __syncthreads();

  const float scky = inn ? (-1.f + (float)(2 * iyn + 1) * (1.f / 64.f)) : 0.f;
  const float sckx = inn ? (-1.f + (float)(2 * ixn + 1) * (1.f / 64.f)) : 0.f;

  if (tid < 49) {
    const int a = tid / 7, bb = tid - a * 7;
    float sy = scky + (float)(a - 3) * (2.f / 64.f) + s_off[2 * tid];
    float sx = sckx + (float)(bb - 3) * (2.f / 64.f) + s_off[2 * tid + 1];
    relbuf[(size_t)q * 128 + 2 * tid]     = f2b((c0 - sy) * 64.f);
    relbuf[(size_t)q * 128 + 2 * tid + 1] = f2b((c1 - sx) * 64.f);
    float gx2 = ((sx + 1.f) * 64.f - 1.f) * 0.5f;
    float gy2 = ((sy + 1.f) * 64.f - 1.f) * 0.5f;
    int ix2 = (int)rintf(gx2), iy2 = (int)rintf(gy2);
    int id = (((unsigned)ix2 < 64u) && ((unsigned)iy2 < 64u)) ? (iy2 * 64 + ix2) : -1;
    s_idx[tid] = id;
    vidx[q * 49 + tid] = id;
  } else if (tid >= 98 && tid < 128) {
    relbuf[(size_t)q * 128 + tid] = 0;
  }
  __syncthreads();

  const float x0f = floorf(gxp), y0f = floorf(gyp);
  const float wx = gxp - x0f, wy = gyp - y0f;
  const int x0 = (int)x0f, y0 = (int)y0f;
  float qc = 0.f;
  #pragma unroll
  for (int t = 0; t < 4; t++) {
    int xi = x0 + (t & 1), yi = y0 + (t >> 1);
    if (((unsigned)xi < 64u) && ((unsigned)yi < 64u)) {
      float w = ((t & 1) ? wx : 1.f - wx) * ((t >> 1) ? wy : 1.f - wy);
      qc += w * fqkv[(size_t)(yi * 64 + xi) * 768 + tid];
    }
  }
  qc *= 0.17677669529663687f;  // 1/sqrt(32)

  const int h = tid >> 5;
  for (int k = 0; k < 49; k++) {
    int id = s_idx[k];
    float kv = (id >= 0) ? fqkv[(size_t)id * 768 + 256 + tid] : 0.f;
    float p = qc * kv;
    p += __shfl_down(p, 16, 32);
    p += __shfl_down(p, 8, 32);
    p += __shfl_down(p, 4, 32);
    p += __shfl_down(p, 2, 32);
    p += __shfl_down(p, 1, 32);
    if ((tid & 31) == 0) attnval[((size_t)q * 49 + k) * 8 + h] = p;
  }

  if (tid < 3) {
    float gx = fminf(fmaxf(gxp, 0.f), 63.f);
    float gy = fminf(fmaxf(gyp, 0.f), 63.f);
    float xf = floorf(gx), yf = floorf(gy);
    float wxs = gx - xf, wys = gy - yf;
    int xa = (int)xf, ya = (int)yf;
    int xb = min(xa + 1, 63), yb = min(ya + 1, 63);
    const float* ch = inp + tid * HW;
    float v = (1.f - wxs) * (1.f - wys) * ch[ya * 64 + xa]
            + wxs * (1.f - wys) * ch[ya * 64 + xb]
            + (1.f - wxs) * wys * ch[yb * 64 + xa]
            + wxs * wys * ch[yb * 64 + xb];
    skipb[q * 3 + tid] = v;
  }
}

// ---------------------------------------------------------------------------
// softmax over 49 taps per head. block 512 (8 waves = 8 heads), grid NQ.
// ---------------------------------------------------------------------------
__global__ __launch_bounds__(512)
void softmax_k(const float* __restrict__ wc, float* __restrict__ attnval)
{
  const int q = blockIdx.x;
  const int tid = threadIdx.x;
  const int hh = tid >> 6, l = tid & 63;
  float v = (l < 49) ? wc[(size_t)q * 49 + l] + attnval[((size_t)q * 49 + l) * 8 + hh]
                     : -1e30f;
  float m = v;
  #pragma unroll
  for (int off = 32; off; off >>= 1) m = fmaxf(m, __shfl_xor(m, off));
  float e = (l < 49) ? expf(v - m) : 0.f;
  float s = e;
  #pragma unroll
  for (int off = 32; off; off >>= 1) s += __shfl_xor(s, off);
  if (l < 49) attnval[((size_t)q * 49 + l) * 8 + hh] = e / s;
}

// ---------------------------------------------------------------------------
// Final: pred = hid2 @ Wi2^T + bi2 + skip. block 256, grid NQ.
// ---------------------------------------------------------------------------
__global__ __launch_bounds__(256)
void final_out(const float* __restrict__ hid2, const float* __restrict__ Wi2,
               const float* __restrict__ bi2, const float* __restrict__ skipb,
               float* __restrict__ out)
{
  const int q = blockIdx.x, c = threadIdx.x;
  __shared__ float part[3][4];
  float hv = hid2[(size_t)q * 256 + c];
  float p0 = hv * Wi2[c], p1 = hv * Wi2[256 + c], p2 = hv * Wi2[512 + c];
  #pragma unroll
  for (int off = 32; off; off >>= 1) {
    p0 += __shfl_xor(p0, off);
    p1 += __shfl_xor(p1, off);
    p2 += __shfl_xor(p2, off);
  }
  if ((c & 63) == 0) {
    int w = c >> 6;
    part[0][w] = p0; part[1][w] = p1; part[2][w] = p2;
  }
  __syncthreads();
  if (c < 3)
    out[q * 3 + c] = bi2[c] + skipb[q * 3 + c]
                   + part[c][0] + part[c][1] + part[c][2] + part[c][3];
}

// ===========================================================================
extern "C" void kernel_launch(void* const* d_in, const int* in_sizes, int n_in,
                              void* d_out, int out_size, void* d_ws, size_t ws_size,
                              hipStream_t stream)
{
  const float* inp    = (const float*)d_in[0];
  const float* coord  = (const float*)d_in[1];
  const float* cell   = (const float*)d_in[2];
  const float* W_enc  = (const float*)d_in[3];
  const float* b_enc  = (const float*)d_in[4];
  const float* W_ch   = (const float*)d_in[5];
  const float* b_ch   = (const float*)d_in[6];
  const float* W_q    = (const float*)d_in[7];
  const float* b_q    = (const float*)d_in[8];
  const float* W_k    = (const float*)d_in[9];
  const float* b_k    = (const float*)d_in[10];
  const float* W_v    = (const float*)d_in[11];
  const float* b_v    = (const float*)d_in[12];
  const float* W_off1 = (const float*)d_in[13];
  const float* b_off1 = (const float*)d_in[14];
  const float* ln_g   = (const float*)d_in[15];
  const float* ln_b   = (const float*)d_in[16];
  const float* W_off2 = (const float*)d_in[17];
  const float* Wc1    = (const float*)d_in[18];
  const float* bc1    = (const float*)d_in[19];
  const float* Wc2    = (const float*)d_in[20];
  const float* bc2    = (const float*)d_in[21];
  const float* Wi1    = (const float*)d_in[22];
  const float* bi1    = (const float*)d_in[23];
  const float* Wi2    = (const float*)d_in[24];
  const float* bi2    = (const float*)d_in[25];

  char* base = (char*)d_ws;
  size_t off = 0;
  auto alloc = [&](size_t bytes) -> char* {
    char* r = base + off;
    off = (off + bytes + 255) & ~(size_t)255;
    return r;
  };

  // --- scratch region (dead before gemm_big runs; Pbuf aliases it) ---
  float* obuf   = (float*)alloc((size_t)HW * 256 * 4);
  u16*   ocg    = (u16*)  alloc((size_t)HW * 256 * 2);
  float* offsb  = (float*)alloc((size_t)HW * 98 * 4);
  u16*   feat1  = (u16*)  alloc((size_t)HW * 64 * 2);
  u16*   feat   = (u16*)  alloc((size_t)HW * 256 * 2);
  u16*   hid1   = (u16*)  alloc((size_t)NQ * 256 * 2);
  float* wcb    = (float*)alloc((size_t)NQ * 49 * 4);
  u16*   relbuf = (u16*)  alloc((size_t)NQ * 128 * 2);
  u16*   Btqkv  = (u16*)  alloc((size_t)768 * 2304 * 2);
  u16*   Btch   = (u16*)  alloc((size_t)256 * 576 * 2);
  u16*   Btoff1 = (u16*)  alloc((size_t)256 * 800 * 2);
  u16*   Btoff2 = (u16*)  alloc((size_t)98 * 256 * 2);
  u16*   Btc1   = (u16*)  alloc((size_t)256 * 128 * 2);
  u16*   Btc2   = (u16*)  alloc((size_t)49 * 256 * 2);
  // split-K partials alias scratch: SPLITK x 4 MB = 33.5 MB
  float* Pbuf = (float*)base;
  {
    size_t need = (size_t)SPLITK * NQ * 256 * 4;
    if (off < need) off = (need + 255) & ~(size_t)255;
  }
  // --- persistent buffers ---
  float* fqkv    = (float*)alloc((size_t)HW * 768 * 4);
  float* attnval = (float*)alloc((size_t)NQ * 49 * 8 * 4);
  int*   vidxb   = (int*)  alloc((size_t)NQ * 49 * 4);
  float* skipb   = (float*)alloc((size_t)NQ * 3 * 4);
  float* hid2    = (float*)alloc((size_t)NQ * 256 * 4);
  u16*   Wi1p    = (u16*)  alloc((size_t)256 * KBIG * 2);
  float* bqkv    = (float*)alloc(768 * 4);
  (void)ws_size; (void)in_sizes; (void)n_in; (void)out_size;

  // --- weight packing ---
  pack_misc<<<(SZ_PACK + 255) / 256, 256, 0, stream>>>(
      W_ch, W_q, W_k, W_v, W_off1, W_off2, Wc1, Wc2, b_q, b_k, b_v,
      Btch, Btqkv, Btoff1, Btoff2, Btc1, Btc2, bqkv);
  pack_cast<<<(256 * KBIG + 255) / 256, 256, 0, stream>>>(Wi1, Wi1p, 256, 12546, KBIG);

  // --- conv stack (implicit im2col) ---
  conv_enc<<<HW, 64, 0, stream>>>(inp, W_enc, b_enc, feat1);
  gemm_conv<3, 6, 1><<<dim3(64, 4, 1), 256, 0, stream>>>(
      feat1, Btch, feat, b_ch, 256, 576, 256, /*bf16*/2, 64, 0, 0, 0, 0);
  gemm_conv<3, 8, 1><<<dim3(64, 12, 1), 256, 0, stream>>>(
      feat, Btqkv, fqkv, bqkv, 768, 2304, 768, 0, 256, 0, 0, 0, 0);
  gemm_conv<5, 5, 2><<<dim3(64, 1, 8), 256, 0, stream>>>(
      feat, Btoff1, obuf, b_off1, 32, 800, 256, 0, 256, 32,
      (long)32 * 800, 32, 32);
  ln_gelu<<<HW, 256, 0, stream>>>(obuf, ln_g, ln_b, ocg);
  gemm_bt<<<dim3(64, 2, 1), 256, 0, stream>>>(ocg, Btoff2, offsb, nullptr,
      98, 256, 98, 0, 0, 0, 0, 0);

  // --- per-query attention path ---
  sampler<<<NQ, 256, 0, stream>>>(coord, fqkv, offsb, inp, attnval, relbuf, vidxb, skipb);
  gemm_bt<<<dim3(64, 4, 1), 256, 0, stream>>>(relbuf, Btc1, hid1, bc1,
      256, 128, 256, /*relu+bf16*/3, 0, 0, 0, 0);
  gemm_bt<<<dim3(64, 1, 1), 256, 0, stream>>>(hid1, Btc2, wcb, bc2,
      49, 256, 49, 0, 0, 0, 0, 0);
  softmax_k<<<NQ, 512, 0, stream>>>(wcb, attnval);

  // --- big MLP: fused gather-A + split-K, tile 64x128 ---
  const int kchunk = ((KBIG / BK + SPLITK - 1) / SPLITK) * BK;  // 1600
  gemm_big<<<dim3(64, 2, SPLITK), 256, 0, stream>>>(
      Wi1p, fqkv, attnval, vidxb, cell, Pbuf, kchunk);
  reduce_sk<<<(NQ * 256 + 255) / 256, 256, 0, stream>>>(
      Pbuf, hid2, bi1, NQ * 256, 256, SPLITK);
  final_out<<<NQ, 256, 0, stream>>>(hid2, Wi2, bi2, skipb, (float*)d_out);
}